// Round 2
// baseline (271.774 us; speedup 1.0000x reference)
//
#include <hip/hip_runtime.h>

// PMField R9: kill the residency tail.
//  - R8 counters: Occupancy 25.7% == avg of (3 blocks/CU phase + 1 block/CU
//    tail): LDS 48KB -> 3-resident, grid 1024 = 4 blocks/CU of work ->
//    wall ~= 2x per-block latency. VALUBusy fell to 55 (still latency-bound).
//  - Fix: drop sA LDS staging; S-plane frags read straight from global like
//    G-frags (64KB shared by ALL blocks -> permanently L2-resident).
//    LDS 48KB -> 16KB (sWF only), __launch_bounds__(256,4) caps VGPR at 128
//    (R8 used 84) -> 4 blocks/CU ALL resident from t=0, no tail, no barrier.
//  - Keeps R8's acc-init fold (zz+cn2 in MFMA acc init, r2=fmax(S,EPS)) and
//    f32 cn2/mu float4 loads.
// Layouts (HW-verified): C/D col=lane&15,row=q*4+r; A[m=lane&15][k=q*8+j];
// B = transpose-dual of A.

#define STEPS 8
#define DTB   0.15f
#define EPSF  1e-4f

typedef short bf16x8 __attribute__((ext_vector_type(8)));
typedef float f32x4  __attribute__((ext_vector_type(4)));
union FragU { int4 i; bf16x8 h; };

__device__ __forceinline__ unsigned bfp(float lo, float hi) { // round pack
    return ((__float_as_uint(lo) + 0x8000u) >> 16) |
           ((__float_as_uint(hi) + 0x8000u) & 0xFFFF0000u);
}
__device__ __forceinline__ unsigned bfpt(float lo, float hi) { // trunc pack
    return (__float_as_uint(lo) >> 16) | (__float_as_uint(hi) & 0xFFFF0000u);
}
__device__ __forceinline__ float med3(float x, float lo, float hi) {
    return __builtin_amdgcn_fmed3f(x, lo, hi);
}

// d_ws layout:
//   int4 [0,    2048)  S-planes: ((c*4+Mt)*2+h)*64 + lane = bf16x8 of -2C[center][dims]
//   int4 [2048, 4096)  G-planes: ((Mt*4+c)*2+h)*64 + lane = bf16x8 of C^T[dim][centers]
//   f32  ws[16384..16640)  cn2[256]   (|c|^2, full precision)
//   f32  ws[16640..16896)  mu[256]
__global__ void pm_prep(const float* __restrict__ centers,
                        const float* __restrict__ mus,
                        unsigned* __restrict__ ws) {
    const int gtid = blockIdx.x * 256 + threadIdx.x;
    if (gtid < 2048) {                       // S-plane frags
        const int c = gtid >> 9, Mt = (gtid >> 7) & 3, h = (gtid >> 6) & 1;
        const int L = gtid & 63, m16 = L & 15, q = L >> 4;
        const float* row = centers + (size_t)(64 * c + 16 * Mt + m16) * 64 + 32 * h + 8 * q;
        uint4 u;
        u.x = bfp(-2.f * row[0], -2.f * row[1]);
        u.y = bfp(-2.f * row[2], -2.f * row[3]);
        u.z = bfp(-2.f * row[4], -2.f * row[5]);
        u.w = bfp(-2.f * row[6], -2.f * row[7]);
        ((uint4*)ws)[gtid] = u;
    } else if (gtid < 4096) {                // G-plane frags (C^T)
        const int i = gtid - 2048;
        const int Mt = i >> 9, c = (i >> 7) & 3, h = (i >> 6) & 1;
        const int L = i & 63, m16 = L & 15, q = L >> 4;
        const float* base = centers + (size_t)(64 * c + 32 * h + 8 * q) * 64 + 16 * Mt + m16;
        uint4 u;
        u.x = bfp(base[0],   base[64]);
        u.y = bfp(base[128], base[192]);
        u.z = bfp(base[256], base[320]);
        u.w = bfp(base[384], base[448]);
        ((uint4*)ws)[gtid] = u;
    } else if (gtid < 4352) {                // cn2 / mu as f32
        const int t = gtid - 4096;
        const float* r = centers + (size_t)t * 64;
        float a0 = 0.f, a1 = 0.f, a2 = 0.f, a3 = 0.f;
#pragma unroll
        for (int d = 0; d < 64; d += 4) {
            a0 = fmaf(r[d],     r[d],     a0);
            a1 = fmaf(r[d + 1], r[d + 1], a1);
            a2 = fmaf(r[d + 2], r[d + 2], a2);
            a3 = fmaf(r[d + 3], r[d + 3], a3);
        }
        float c2 = (a0 + a1) + (a2 + a3);
        ((float*)ws)[16384 + t] = c2;
        ((float*)ws)[16640 + t] = mus[t];
    }
}

__global__ __launch_bounds__(256, 4)
void pm_main(const float* __restrict__ z_in,
             const unsigned* __restrict__ ws,
             float* __restrict__ z_out) {
    __shared__ int4 sWF[4][4][64];     // 16 KB: wave-private B-frag planes

    const int4* wsA = (const int4*)ws;        // S-plane frags (L2-resident)
    const int4* wsG = wsA + 2048;             // G-plane frags (L2-resident)
    const float* wsC  = (const float*)ws + 16384;
    const float* wsMu = (const float*)ws + 16640;

    const int tid  = threadIdx.x;
    const int lane = tid & 63;
    const int w    = tid >> 6;
    const int m16  = lane & 15;
    const int q    = lane >> 4;

    const int pbase = blockIdx.x * 128;   // 128 particles/block, 32/wave

    // z state in C/D layout: lane holds dims {16Mt+4q..+3} x particles {m16, m16+16}
    f32x4 z[4][2];
#pragma unroll
    for (int Mt = 0; Mt < 4; ++Mt)
#pragma unroll
        for (int Nt = 0; Nt < 2; ++Nt)
            z[Mt][Nt] = *(const f32x4*)(z_in + (size_t)(pbase + 32 * w + m16 + 16 * Nt) * 64
                                        + 16 * Mt + 4 * q);

    unsigned* wp = (unsigned*)&sWF[w][0][0];   // wave-private, 1024 uints

#pragma unroll 1
    for (int s = 0; s < STEPS; ++s) {
        // zz per particle (butterfly over q groups)
        float zzp[2];
#pragma unroll
        for (int Nt = 0; Nt < 2; ++Nt) {
            float a = 0.f;
#pragma unroll
            for (int Mt = 0; Mt < 4; ++Mt)
#pragma unroll
                for (int r = 0; r < 4; ++r) a = fmaf(z[Mt][Nt][r], z[Mt][Nt][r], a);
            a += __shfl_xor(a, 16, 64);
            a += __shfl_xor(a, 32, 64);
            zzp[Nt] = a;
        }

        // z (C/D regs) -> B-frag planes: scatter write (wave-internal, no barrier)
#pragma unroll
        for (int Mt = 0; Mt < 4; ++Mt) {
            const int Kt = Mt >> 1;
            const int qt = (2 * Mt + (q >> 1)) & 3;
#pragma unroll
            for (int Nt = 0; Nt < 2; ++Nt) {
                const int pos = ((Kt * 2 + Nt) * 64 + m16 + 16 * qt) * 4 + 2 * (q & 1);
                *(uint2*)(wp + pos) = make_uint2(bfp(z[Mt][Nt][0], z[Mt][Nt][1]),
                                                 bfp(z[Mt][Nt][2], z[Mt][Nt][3]));
            }
        }
        FragU zf[2][2];
#pragma unroll
        for (int Kt = 0; Kt < 2; ++Kt)
#pragma unroll
            for (int Nt = 0; Nt < 2; ++Nt)
                zf[Kt][Nt].i = sWF[w][Kt * 2 + Nt][lane];   // lane-linear read

        f32x4 g[4][2];
#pragma unroll
        for (int Mt = 0; Mt < 4; ++Mt)
#pragma unroll
            for (int Nt = 0; Nt < 2; ++Nt) g[Mt][Nt] = (f32x4){0.f, 0.f, 0.f, 0.f};
        float nacc[2] = {0.f, 0.f}, swp[2] = {0.f, 0.f};

#pragma unroll 1
        for (int c = 0; c < 4; ++c) {          // 4 chunks x 64 centers
            // S-phase, fused per Mt; acc INIT carries zz + cn2 (C/D row match)
#pragma unroll
            for (int Mt = 0; Mt < 4; ++Mt) {
                FragU a0, a1;
                a0.i = wsA[((c * 4 + Mt) * 2 + 0) * 64 + lane];   // L2-resident
                a1.i = wsA[((c * 4 + Mt) * 2 + 1) * 64 + lane];
                const float4 cn4 = *(const float4*)(wsC  + 64 * c + 16 * Mt + 4 * q);
                const float4 mu4 = *(const float4*)(wsMu + 64 * c + 16 * Mt + 4 * q);
                f32x4 S[2];
#pragma unroll
                for (int Nt = 0; Nt < 2; ++Nt) {
                    f32x4 acc;
                    acc[0] = zzp[Nt] + cn4.x;
                    acc[1] = zzp[Nt] + cn4.y;
                    acc[2] = zzp[Nt] + cn4.z;
                    acc[3] = zzp[Nt] + cn4.w;
                    acc = __builtin_amdgcn_mfma_f32_16x16x32_bf16(a0.h, zf[0][Nt].h, acc, 0, 0, 0);
                    acc = __builtin_amdgcn_mfma_f32_16x16x32_bf16(a1.h, zf[1][Nt].h, acc, 0, 0, 0);
                    S[Nt] = acc;   // S = zz + |c|^2 - 2 z.c; row = center 64c+16Mt+4q+r
                }

                float wv[2][4];
#pragma unroll
                for (int r = 0; r < 4; ++r) {
                    const float mu = (r == 0) ? mu4.x : (r == 1) ? mu4.y
                                   : (r == 2) ? mu4.z : mu4.w;
#pragma unroll
                    for (int Nt = 0; Nt < 2; ++Nt) {
                        float r2  = fmaxf(S[Nt][r], EPSF);      // == max(.,0)+eps here
                        float rin = __builtin_amdgcn_rsqf(r2);
                        float mur = mu * rin;
                        nacc[Nt] += mur;
                        float wval = mur * rin * rin;           // mu / r^3
                        swp[Nt] += wval;
                        wv[Nt][r] = wval;
                    }
                }
                const int Kt = Mt >> 1;
                const int qt = (2 * Mt + (q >> 1)) & 3;
#pragma unroll
                for (int Nt = 0; Nt < 2; ++Nt) {
                    const int pos = ((Kt * 2 + Nt) * 64 + m16 + 16 * qt) * 4 + 2 * (q & 1);
                    *(uint2*)(wp + pos) = make_uint2(bfpt(wv[Nt][0], wv[Nt][1]),
                                                     bfpt(wv[Nt][2], wv[Nt][3]));
                }
            }

            // G-phase: wf frags (lane-linear LDS) + global ga frags (L2)
            FragU wf[2][2];
#pragma unroll
            for (int Kt = 0; Kt < 2; ++Kt)
#pragma unroll
                for (int Nt = 0; Nt < 2; ++Nt)
                    wf[Kt][Nt].i = sWF[w][Kt * 2 + Nt][lane];
#pragma unroll
            for (int Mt = 0; Mt < 4; ++Mt) {
                FragU ga0, ga1;
                ga0.i = wsG[((Mt * 4 + c) * 2 + 0) * 64 + lane];
                ga1.i = wsG[((Mt * 4 + c) * 2 + 1) * 64 + lane];
#pragma unroll
                for (int Nt = 0; Nt < 2; ++Nt) {
                    g[Mt][Nt] = __builtin_amdgcn_mfma_f32_16x16x32_bf16(ga0.h, wf[0][Nt].h, g[Mt][Nt], 0, 0, 0);
                    g[Mt][Nt] = __builtin_amdgcn_mfma_f32_16x16x32_bf16(ga1.h, wf[1][Nt].h, g[Mt][Nt], 0, 0, 0);
                }
            }
        }

        // reduce n, sw across q groups; update z
        float tco[2], swf[2];
#pragma unroll
        for (int Nt = 0; Nt < 2; ++Nt) {
            float a = nacc[Nt];
            a += __shfl_xor(a, 16, 64);
            a += __shfl_xor(a, 32, 64);
            float b = swp[Nt];
            b += __shfl_xor(b, 16, 64);
            b += __shfl_xor(b, 32, 64);
            tco[Nt] = DTB * __builtin_amdgcn_rcpf(1.f + a);
            swf[Nt] = b;
        }
#pragma unroll
        for (int Mt = 0; Mt < 4; ++Mt)
#pragma unroll
            for (int Nt = 0; Nt < 2; ++Nt)
#pragma unroll
                for (int r = 0; r < 4; ++r) {
                    float gd = fmaf(-swf[Nt], z[Mt][Nt][r], g[Mt][Nt][r]);
                    z[Mt][Nt][r] = med3(fmaf(tco[Nt], gd, z[Mt][Nt][r]), -3.f, 3.f);
                }
    }

    // direct C/D-layout store (16B segments, rows covered across lanes)
#pragma unroll
    for (int Mt = 0; Mt < 4; ++Mt)
#pragma unroll
        for (int Nt = 0; Nt < 2; ++Nt)
            *(f32x4*)(z_out + (size_t)(pbase + 32 * w + m16 + 16 * Nt) * 64
                      + 16 * Mt + 4 * q) = z[Mt][Nt];
}

extern "C" void kernel_launch(void* const* d_in, const int* in_sizes, int n_in,
                              void* d_out, int out_size, void* d_ws, size_t ws_size,
                              hipStream_t stream) {
    const float* z       = (const float*)d_in[0];
    const float* centers = (const float*)d_in[1];
    const float* mus     = (const float*)d_in[2];
    float* out           = (float*)d_out;
    unsigned* ws         = (unsigned*)d_ws;

    pm_prep<<<dim3(17), dim3(256), 0, stream>>>(centers, mus, ws);
    // 131072 particles / 128 per block (4 waves x 32) = 1024 blocks = 4/CU,
    // all resident (LDS 16KB, VGPR<=128)
    pm_main<<<dim3(1024), dim3(256), 0, stream>>>(z, ws, out);
}

// Round 3
// 230.331 us; speedup vs baseline: 1.1799x; 1.1799x over previous
//
#include <hip/hip_runtime.h>

// PMField R10: 4-resident via LDS diet, NOT via launch-bounds caps.
//  - R9 post-mortem: __launch_bounds__(256,4) re-triggered the spill
//    heuristic (VGPR clamped 84->64, WRITE_SIZE 33->273MB scratch traffic,
//    dur 180->222us). Any cap <=128 spills this body; (256,2)/84 VGPR is
//    the safe point (R8).
//  - R8 residency math: LDS 48KB -> 3 blocks/CU vs 4 blocks/CU of work ->
//    1-block tail ~= half the wall. Fix here: sA holds only chunks 0..2
//    (24KB); chunk 3 S-frags read from global (L2-resident, same path as
//    G-frags). LDS = 24 + 16 = 40960B -> 4 x 40960 = 163840 = exactly the
//    160KiB pool -> 4 blocks/CU, VGPR residency floor(512/84)=6 waves/SIMD
//    -> all 16 waves/CU resident from t=0, zero tail.
//  - Keeps R8's acc-init fold (zz+cn2 in MFMA acc init, r2=fmax(S,EPS)),
//    f32 cn2/mu float4 loads, unroll 1 on chunk loop.
// Layouts (HW-verified): C/D col=lane&15,row=q*4+r; A[m=lane&15][k=q*8+j];
// B = transpose-dual of A.

#define STEPS 8
#define DTB   0.15f
#define EPSF  1e-4f

typedef short bf16x8 __attribute__((ext_vector_type(8)));
typedef float f32x4  __attribute__((ext_vector_type(4)));
union FragU { int4 i; bf16x8 h; };

__device__ __forceinline__ unsigned bfp(float lo, float hi) { // round pack
    return ((__float_as_uint(lo) + 0x8000u) >> 16) |
           ((__float_as_uint(hi) + 0x8000u) & 0xFFFF0000u);
}
__device__ __forceinline__ unsigned bfpt(float lo, float hi) { // trunc pack
    return (__float_as_uint(lo) >> 16) | (__float_as_uint(hi) & 0xFFFF0000u);
}
__device__ __forceinline__ float med3(float x, float lo, float hi) {
    return __builtin_amdgcn_fmed3f(x, lo, hi);
}

// d_ws layout:
//   int4 [0,    2048)  S-planes: ((c*4+Mt)*2+h)*64 + lane = bf16x8 of -2C[center][dims]
//   int4 [2048, 4096)  G-planes: ((Mt*4+c)*2+h)*64 + lane = bf16x8 of C^T[dim][centers]
//   f32  ws[16384..16640)  cn2[256]   (|c|^2, full precision)
//   f32  ws[16640..16896)  mu[256]
__global__ void pm_prep(const float* __restrict__ centers,
                        const float* __restrict__ mus,
                        unsigned* __restrict__ ws) {
    const int gtid = blockIdx.x * 256 + threadIdx.x;
    if (gtid < 2048) {                       // S-plane frags
        const int c = gtid >> 9, Mt = (gtid >> 7) & 3, h = (gtid >> 6) & 1;
        const int L = gtid & 63, m16 = L & 15, q = L >> 4;
        const float* row = centers + (size_t)(64 * c + 16 * Mt + m16) * 64 + 32 * h + 8 * q;
        uint4 u;
        u.x = bfp(-2.f * row[0], -2.f * row[1]);
        u.y = bfp(-2.f * row[2], -2.f * row[3]);
        u.z = bfp(-2.f * row[4], -2.f * row[5]);
        u.w = bfp(-2.f * row[6], -2.f * row[7]);
        ((uint4*)ws)[gtid] = u;
    } else if (gtid < 4096) {                // G-plane frags (C^T)
        const int i = gtid - 2048;
        const int Mt = i >> 9, c = (i >> 7) & 3, h = (i >> 6) & 1;
        const int L = i & 63, m16 = L & 15, q = L >> 4;
        const float* base = centers + (size_t)(64 * c + 32 * h + 8 * q) * 64 + 16 * Mt + m16;
        uint4 u;
        u.x = bfp(base[0],   base[64]);
        u.y = bfp(base[128], base[192]);
        u.z = bfp(base[256], base[320]);
        u.w = bfp(base[384], base[448]);
        ((uint4*)ws)[gtid] = u;
    } else if (gtid < 4352) {                // cn2 / mu as f32
        const int t = gtid - 4096;
        const float* r = centers + (size_t)t * 64;
        float a0 = 0.f, a1 = 0.f, a2 = 0.f, a3 = 0.f;
#pragma unroll
        for (int d = 0; d < 64; d += 4) {
            a0 = fmaf(r[d],     r[d],     a0);
            a1 = fmaf(r[d + 1], r[d + 1], a1);
            a2 = fmaf(r[d + 2], r[d + 2], a2);
            a3 = fmaf(r[d + 3], r[d + 3], a3);
        }
        float c2 = (a0 + a1) + (a2 + a3);
        ((float*)ws)[16384 + t] = c2;
        ((float*)ws)[16640 + t] = mus[t];
    }
}

__global__ __launch_bounds__(256, 2)
void pm_main(const float* __restrict__ z_in,
             const unsigned* __restrict__ ws,
             float* __restrict__ z_out) {
    __shared__ int4 sA[1536];          // 24 KB: S-plane frags, chunks 0..2 only
    __shared__ int4 sWF[4][4][64];     // 16 KB: wave-private B-frag planes
                                       // total 40960 B -> 4 blocks/CU

    const int4* wsA = (const int4*)ws;        // S-plane frags (chunk 3 from here)
    const int4* wsG = wsA + 2048;             // G-plane frags (L2-resident)
    const float* wsC  = (const float*)ws + 16384;
    const float* wsMu = (const float*)ws + 16640;

    const int tid  = threadIdx.x;
    const int lane = tid & 63;
    const int w    = tid >> 6;
    const int m16  = lane & 15;
    const int q    = lane >> 4;

    // copy S planes for chunks 0..2 to LDS (lane-linear, coalesced)
#pragma unroll
    for (int i = 0; i < 6; ++i) sA[i * 256 + tid] = wsA[i * 256 + tid];
    __syncthreads();

    const int pbase = blockIdx.x * 128;   // 128 particles/block, 32/wave

    // z state in C/D layout: lane holds dims {16Mt+4q..+3} x particles {m16, m16+16}
    f32x4 z[4][2];
#pragma unroll
    for (int Mt = 0; Mt < 4; ++Mt)
#pragma unroll
        for (int Nt = 0; Nt < 2; ++Nt)
            z[Mt][Nt] = *(const f32x4*)(z_in + (size_t)(pbase + 32 * w + m16 + 16 * Nt) * 64
                                        + 16 * Mt + 4 * q);

    unsigned* wp = (unsigned*)&sWF[w][0][0];   // wave-private, 1024 uints

#pragma unroll 1
    for (int s = 0; s < STEPS; ++s) {
        // zz per particle (butterfly over q groups)
        float zzp[2];
#pragma unroll
        for (int Nt = 0; Nt < 2; ++Nt) {
            float a = 0.f;
#pragma unroll
            for (int Mt = 0; Mt < 4; ++Mt)
#pragma unroll
                for (int r = 0; r < 4; ++r) a = fmaf(z[Mt][Nt][r], z[Mt][Nt][r], a);
            a += __shfl_xor(a, 16, 64);
            a += __shfl_xor(a, 32, 64);
            zzp[Nt] = a;
        }

        // z (C/D regs) -> B-frag planes: scatter write (wave-internal, no barrier)
#pragma unroll
        for (int Mt = 0; Mt < 4; ++Mt) {
            const int Kt = Mt >> 1;
            const int qt = (2 * Mt + (q >> 1)) & 3;
#pragma unroll
            for (int Nt = 0; Nt < 2; ++Nt) {
                const int pos = ((Kt * 2 + Nt) * 64 + m16 + 16 * qt) * 4 + 2 * (q & 1);
                *(uint2*)(wp + pos) = make_uint2(bfp(z[Mt][Nt][0], z[Mt][Nt][1]),
                                                 bfp(z[Mt][Nt][2], z[Mt][Nt][3]));
            }
        }
        FragU zf[2][2];
#pragma unroll
        for (int Kt = 0; Kt < 2; ++Kt)
#pragma unroll
            for (int Nt = 0; Nt < 2; ++Nt)
                zf[Kt][Nt].i = sWF[w][Kt * 2 + Nt][lane];   // lane-linear read

        f32x4 g[4][2];
#pragma unroll
        for (int Mt = 0; Mt < 4; ++Mt)
#pragma unroll
            for (int Nt = 0; Nt < 2; ++Nt) g[Mt][Nt] = (f32x4){0.f, 0.f, 0.f, 0.f};
        float nacc[2] = {0.f, 0.f}, swp[2] = {0.f, 0.f};

#pragma unroll 1
        for (int c = 0; c < 4; ++c) {          // 4 chunks x 64 centers
            // S-phase, fused per Mt; acc INIT carries zz + cn2 (C/D row match)
#pragma unroll
            for (int Mt = 0; Mt < 4; ++Mt) {
                FragU a0, a1;
                if (c < 3) {                   // LDS copy (chunks 0..2)
                    a0.i = sA[((c * 4 + Mt) * 2 + 0) * 64 + lane];
                    a1.i = sA[((c * 4 + Mt) * 2 + 1) * 64 + lane];
                } else {                       // chunk 3: straight from L2
                    a0.i = wsA[((c * 4 + Mt) * 2 + 0) * 64 + lane];
                    a1.i = wsA[((c * 4 + Mt) * 2 + 1) * 64 + lane];
                }
                const float4 cn4 = *(const float4*)(wsC  + 64 * c + 16 * Mt + 4 * q);
                const float4 mu4 = *(const float4*)(wsMu + 64 * c + 16 * Mt + 4 * q);
                f32x4 S[2];
#pragma unroll
                for (int Nt = 0; Nt < 2; ++Nt) {
                    f32x4 acc;
                    acc[0] = zzp[Nt] + cn4.x;
                    acc[1] = zzp[Nt] + cn4.y;
                    acc[2] = zzp[Nt] + cn4.z;
                    acc[3] = zzp[Nt] + cn4.w;
                    acc = __builtin_amdgcn_mfma_f32_16x16x32_bf16(a0.h, zf[0][Nt].h, acc, 0, 0, 0);
                    acc = __builtin_amdgcn_mfma_f32_16x16x32_bf16(a1.h, zf[1][Nt].h, acc, 0, 0, 0);
                    S[Nt] = acc;   // S = zz + |c|^2 - 2 z.c; row = center 64c+16Mt+4q+r
                }

                float wv[2][4];
#pragma unroll
                for (int r = 0; r < 4; ++r) {
                    const float mu = (r == 0) ? mu4.x : (r == 1) ? mu4.y
                                   : (r == 2) ? mu4.z : mu4.w;
#pragma unroll
                    for (int Nt = 0; Nt < 2; ++Nt) {
                        float r2  = fmaxf(S[Nt][r], EPSF);      // == max(.,0)+eps here
                        float rin = __builtin_amdgcn_rsqf(r2);
                        float mur = mu * rin;
                        nacc[Nt] += mur;
                        float wval = mur * rin * rin;           // mu / r^3
                        swp[Nt] += wval;
                        wv[Nt][r] = wval;
                    }
                }
                const int Kt = Mt >> 1;
                const int qt = (2 * Mt + (q >> 1)) & 3;
#pragma unroll
                for (int Nt = 0; Nt < 2; ++Nt) {
                    const int pos = ((Kt * 2 + Nt) * 64 + m16 + 16 * qt) * 4 + 2 * (q & 1);
                    *(uint2*)(wp + pos) = make_uint2(bfpt(wv[Nt][0], wv[Nt][1]),
                                                     bfpt(wv[Nt][2], wv[Nt][3]));
                }
            }

            // G-phase: wf frags (lane-linear LDS) + global ga frags (L2)
            FragU wf[2][2];
#pragma unroll
            for (int Kt = 0; Kt < 2; ++Kt)
#pragma unroll
                for (int Nt = 0; Nt < 2; ++Nt)
                    wf[Kt][Nt].i = sWF[w][Kt * 2 + Nt][lane];
#pragma unroll
            for (int Mt = 0; Mt < 4; ++Mt) {
                FragU ga0, ga1;
                ga0.i = wsG[((Mt * 4 + c) * 2 + 0) * 64 + lane];
                ga1.i = wsG[((Mt * 4 + c) * 2 + 1) * 64 + lane];
#pragma unroll
                for (int Nt = 0; Nt < 2; ++Nt) {
                    g[Mt][Nt] = __builtin_amdgcn_mfma_f32_16x16x32_bf16(ga0.h, wf[0][Nt].h, g[Mt][Nt], 0, 0, 0);
                    g[Mt][Nt] = __builtin_amdgcn_mfma_f32_16x16x32_bf16(ga1.h, wf[1][Nt].h, g[Mt][Nt], 0, 0, 0);
                }
            }
        }

        // reduce n, sw across q groups; update z
        float tco[2], swf[2];
#pragma unroll
        for (int Nt = 0; Nt < 2; ++Nt) {
            float a = nacc[Nt];
            a += __shfl_xor(a, 16, 64);
            a += __shfl_xor(a, 32, 64);
            float b = swp[Nt];
            b += __shfl_xor(b, 16, 64);
            b += __shfl_xor(b, 32, 64);
            tco[Nt] = DTB * __builtin_amdgcn_rcpf(1.f + a);
            swf[Nt] = b;
        }
#pragma unroll
        for (int Mt = 0; Mt < 4; ++Mt)
#pragma unroll
            for (int Nt = 0; Nt < 2; ++Nt)
#pragma unroll
                for (int r = 0; r < 4; ++r) {
                    float gd = fmaf(-swf[Nt], z[Mt][Nt][r], g[Mt][Nt][r]);
                    z[Mt][Nt][r] = med3(fmaf(tco[Nt], gd, z[Mt][Nt][r]), -3.f, 3.f);
                }
    }

    // direct C/D-layout store (16B segments, rows covered across lanes)
#pragma unroll
    for (int Mt = 0; Mt < 4; ++Mt)
#pragma unroll
        for (int Nt = 0; Nt < 2; ++Nt)
            *(f32x4*)(z_out + (size_t)(pbase + 32 * w + m16 + 16 * Nt) * 64
                      + 16 * Mt + 4 * q) = z[Mt][Nt];
}

extern "C" void kernel_launch(void* const* d_in, const int* in_sizes, int n_in,
                              void* d_out, int out_size, void* d_ws, size_t ws_size,
                              hipStream_t stream) {
    const float* z       = (const float*)d_in[0];
    const float* centers = (const float*)d_in[1];
    const float* mus     = (const float*)d_in[2];
    float* out           = (float*)d_out;
    unsigned* ws         = (unsigned*)d_ws;

    pm_prep<<<dim3(17), dim3(256), 0, stream>>>(centers, mus, ws);
    // 131072 particles / 128 per block (4 waves x 32) = 1024 blocks = 4/CU,
    // all resident (LDS 40960B x 4 = 160KiB exactly, VGPR ~84 at (256,2))
    pm_main<<<dim3(1024), dim3(256), 0, stream>>>(z, ws, out);
}